// Round 23
// baseline (40.917 us; speedup 1.0000x reference)
//
#include <hip/hip_runtime.h>
#include <cstdint>
#include <cstddef>

// LSTMCreature, seq_len=1, h0=c0=0:
//   per layer: g = x @ Wih(gate rows).T + (bih+bhh); h = sig(go)*tanh(sig(gi)*tanh(gg))
//   f-gate skipped (multiplies c0=0), W_hh unused (h0=0).
// R23 = R22 (full fusion + rcp epilogue + T5 setprio, 39.5us) + GATE-SPLIT
// register relief: 1024-thread blocks are hard-capped at 128 regs/wave
// (4 waves/SIMD, m69 pool); the 64-AGPR 3-gate accumulator left only ~60 arch
// regs -> ~6 loads in flight (R18 VGPR=60), too shallow for ~250cy W-load
// latency. Split each layer: pass1 gates {i,g} (acc 32 f32) -> c2 in 16 f32
// regs; pass2 gate {o} (acc 16). Peak acc 64->32 regs => ~2x load window.
// Each gate's MFMA K-sequence unchanged -> bit-identical numerics.

#define NROWS 16384
#define HSZ   256

typedef _Float16 half8  __attribute__((ext_vector_type(8)));
typedef _Float16 half4v __attribute__((ext_vector_type(4)));
typedef float    f32x4  __attribute__((ext_vector_type(4)));

__device__ __forceinline__ float frcp(float x)  { return __builtin_amdgcn_rcpf(x); }
__device__ __forceinline__ float fsig(float x)  { return frcp(1.f + __expf(-x)); }
__device__ __forceinline__ float ftanh(float x) { return 1.f - 2.f * frcp(__expf(2.f * x) + 1.f); }

__device__ __forceinline__ int gate_remap(int row) {   // 768-row id -> 1024-row src (gates i,g,o)
    int g8 = row >> 8;
    int gate = (g8 == 0) ? 0 : g8 + 1;
    return gate * 256 + (row & 255);
}

// ---------------- fused prep: everything -> frag-linear fp16 ----------------
// frag layout: elem (row,k) -> ((ru*NT+kt)*64 + lane)*8 + (k&7),
// lane = (row&15) | (((k>>3)&3)<<4), ru = row>>4, kt = k>>5.

#define PS0 262144            /* x: 16384*128/8 half8-groups */
#define PS1 (PS0 + 12288)     /* W0: 768*128/8 */
#define PS2 (PS1 + 24576)     /* W1: 768*256/8 */
#define PS3 (PS2 + 24576)     /* W2 */
#define PS4 (PS3 + 2304)      /* bsums */
#define PS5 (PS4 + 2048)      /* fcW: 64*256/8 frag-linear */

__global__ __launch_bounds__(256)
void prep_all_kernel(const float* __restrict__ x,
                     const float* __restrict__ W0, const float* __restrict__ b0i, const float* __restrict__ b0h,
                     const float* __restrict__ W1, const float* __restrict__ b1i, const float* __restrict__ b1h,
                     const float* __restrict__ W2, const float* __restrict__ b2i, const float* __restrict__ b2h,
                     const float* __restrict__ fcW,
                     _Float16* __restrict__ xf,
                     _Float16* __restrict__ W0f, _Float16* __restrict__ W1f, _Float16* __restrict__ W2f,
                     float* __restrict__ bs0, float* __restrict__ bs1, float* __restrict__ bs2,
                     _Float16* __restrict__ fWf)
{
    const int gid = blockIdx.x * 256 + threadIdx.x;
    if (gid < PS0) {
        int row = gid >> 4, kg = gid & 15;            // kg: 8-elem k-group
        const float* s = x + (size_t)row * 128 + kg * 8;
        f32x4 v0 = *(const f32x4*)s, v1 = *(const f32x4*)(s + 4);
        half8 h;
#pragma unroll
        for (int j = 0; j < 4; ++j) { h[j] = (_Float16)v0[j]; h[4 + j] = (_Float16)v1[j]; }
        int lane = (row & 15) | ((kg & 3) << 4);
        size_t idx = (((size_t)(row >> 4) * 4 + (kg >> 2)) * 64 + lane) * 8;
        *(half8*)(xf + idx) = h;
    } else if (gid < PS3) {
        const float* W; _Float16* Wf; int j, K, r768, kg, NTw;
        if (gid < PS1)      { j = gid - PS0; K = 128; W = W0; Wf = W0f; r768 = j >> 4; kg = j & 15; NTw = 4; }
        else if (gid < PS2) { j = gid - PS1; K = 256; W = W1; Wf = W1f; r768 = j >> 5; kg = j & 31; NTw = 8; }
        else                { j = gid - PS2; K = 256; W = W2; Wf = W2f; r768 = j >> 5; kg = j & 31; NTw = 8; }
        int src = gate_remap(r768);
        const float* s = W + (size_t)src * K + kg * 8;
        f32x4 v0 = *(const f32x4*)s, v1 = *(const f32x4*)(s + 4);
        half8 h;
#pragma unroll
        for (int jj = 0; jj < 4; ++jj) { h[jj] = (_Float16)v0[jj]; h[4 + jj] = (_Float16)v1[jj]; }
        int lane = (r768 & 15) | ((kg & 3) << 4);
        size_t idx = (((size_t)(r768 >> 4) * NTw + (kg >> 2)) * 64 + lane) * 8;
        *(half8*)(Wf + idx) = h;
    } else if (gid < PS4) {
        int j = gid - PS3;
        int l = (j >= 1536) ? 2 : (j >= 768 ? 1 : 0);
        int r = j - l * 768;
        int src = gate_remap(r);
        const float* bi = (l == 0) ? b0i : (l == 1) ? b1i : b2i;
        const float* bh = (l == 0) ? b0h : (l == 1) ? b1h : b2h;
        float* bs       = (l == 0) ? bs0 : (l == 1) ? bs1 : bs2;
        bs[r] = bi[src] + bh[src];
    } else if (gid < PS5) {
        int j = gid - PS4;            // 0..2047: fcW 64 rows x 32 kgroups -> frag-linear
        int r64 = j >> 5, kg = j & 31;
        const float* s = fcW + (size_t)r64 * 256 + kg * 8;
        f32x4 v0 = *(const f32x4*)s, v1 = *(const f32x4*)(s + 4);
        half8 h;
#pragma unroll
        for (int jj = 0; jj < 4; ++jj) { h[jj] = (_Float16)v0[jj]; h[4 + jj] = (_Float16)v1[jj]; }
        int lane = (r64 & 15) | ((kg & 3) << 4);
        size_t idx = (((size_t)(r64 >> 4) * 8 + (kg >> 2)) * 64 + lane) * 8;
        *(half8*)(fWf + idx) = h;
    }
}

// ---------------- mega kernel: 3 layers (gate-split) + fc, one block / 64-row slab ----------------
// 1024 threads = 16 waves; wave w = n-unit nu (0..15). Block b owns rows
// b*64..b*64+63. h1/h2/h3 ping-pong in LDS frag layout:
//   frag (fmLocal, kt) at ((fmLocal*8 + kt)*64 + lane)*8 halfs.
// Per layer: pass1 gates {i,g} -> c2 in regs; pass2 gate {o} -> h to LDS.

__global__ __launch_bounds__(1024, 4)
void mega_kernel(const _Float16* __restrict__ xf,
                 const _Float16* __restrict__ W0f, const float* __restrict__ bs0,
                 const _Float16* __restrict__ W1f, const float* __restrict__ bs1,
                 const _Float16* __restrict__ W2f, const float* __restrict__ bs2,
                 const _Float16* __restrict__ fWf, const float* __restrict__ fcb,
                 float* __restrict__ out)
{
    __shared__ __align__(16) _Float16 hP[2][64 * 256];   // 32KB each, frag layout

    const int t    = threadIdx.x;
    const int lane = t & 63;
    const int w    = t >> 6;        // wave = nu
    const int lrow = lane & 15;
    const int lkb  = lane >> 4;
    const int b    = blockIdx.x;

    const int kt_o   = w >> 1;
    const int lane_o = lrow | ((((w & 1) << 1) | (lkb >> 1)) << 4);
    const int elem   = (lkb & 1) * 4;
    const int nbase  = w * 16 + lkb * 4;

    // LAYER_BODY(NT, APTR, AEXPR_STRIDE, WPTR, WSTRIDE, BS, DST):
    //  pass1: gates 0,1 -> c2 ; pass2: gate 2 -> h stored to DST.
#define LAYER_BODY(NT, pAbase, ASTR, pWbase, WSTR, BS, DST)                       \
    {                                                                             \
        const f32x4 bI = *(const f32x4*)((BS) + nbase);                           \
        const f32x4 bG = *(const f32x4*)((BS) + 256 + nbase);                     \
        const f32x4 bO = *(const f32x4*)((BS) + 512 + nbase);                     \
        f32x4 c2[4];                                                              \
        {                                                                         \
            f32x4 acc[2][4];                                                      \
            _Pragma("unroll")                                                     \
            for (int g = 0; g < 2; ++g)                                           \
                _Pragma("unroll")                                                 \
                for (int fm = 0; fm < 4; ++fm) acc[g][fm] = (f32x4)0.f;           \
            _Pragma("unroll")                                                     \
            for (int kt = 0; kt < (NT); ++kt) {                                   \
                half8 a0 = *(const half8*)((pAbase) + (size_t)(0 * (ASTR) + kt) * 512); \
                half8 a1 = *(const half8*)((pAbase) + (size_t)(1 * (ASTR) + kt) * 512); \
                half8 a2 = *(const half8*)((pAbase) + (size_t)(2 * (ASTR) + kt) * 512); \
                half8 a3 = *(const half8*)((pAbase) + (size_t)(3 * (ASTR) + kt) * 512); \
                half8 wi = *(const half8*)((pWbase) + (size_t)(0 * (WSTR) + kt) * 512); \
                half8 wg = *(const half8*)((pWbase) + (size_t)(1 * (WSTR) + kt) * 512); \
                __builtin_amdgcn_s_setprio(1);                                    \
                acc[0][0] = __builtin_amdgcn_mfma_f32_16x16x32_f16(wi, a0, acc[0][0], 0, 0, 0); \
                acc[0][1] = __builtin_amdgcn_mfma_f32_16x16x32_f16(wi, a1, acc[0][1], 0, 0, 0); \
                acc[0][2] = __builtin_amdgcn_mfma_f32_16x16x32_f16(wi, a2, acc[0][2], 0, 0, 0); \
                acc[0][3] = __builtin_amdgcn_mfma_f32_16x16x32_f16(wi, a3, acc[0][3], 0, 0, 0); \
                acc[1][0] = __builtin_amdgcn_mfma_f32_16x16x32_f16(wg, a0, acc[1][0], 0, 0, 0); \
                acc[1][1] = __builtin_amdgcn_mfma_f32_16x16x32_f16(wg, a1, acc[1][1], 0, 0, 0); \
                acc[1][2] = __builtin_amdgcn_mfma_f32_16x16x32_f16(wg, a2, acc[1][2], 0, 0, 0); \
                acc[1][3] = __builtin_amdgcn_mfma_f32_16x16x32_f16(wg, a3, acc[1][3], 0, 0, 0); \
                __builtin_amdgcn_s_setprio(0);                                    \
            }                                                                     \
            _Pragma("unroll")                                                     \
            for (int fm = 0; fm < 4; ++fm)                                        \
                _Pragma("unroll")                                                 \
                for (int j = 0; j < 4; ++j) {                                     \
                    float gi = acc[0][fm][j] + bI[j];                             \
                    float gg = acc[1][fm][j] + bG[j];                             \
                    c2[fm][j] = fsig(gi) * ftanh(gg);                             \
                }                                                                 \
        }                                                                         \
        {                                                                         \
            f32x4 acco[4];                                                        \
            _Pragma("unroll")                                                     \
            for (int fm = 0; fm < 4; ++fm) acco[fm] = (f32x4)0.f;                 \
            _Pragma("unroll")                                                     \
            for (int kt = 0; kt < (NT); ++kt) {                                   \
                half8 a0 = *(const half8*)((pAbase) + (size_t)(0 * (ASTR) + kt) * 512); \
                half8 a1 = *(const half8*)((pAbase) + (size_t)(1 * (ASTR) + kt) * 512); \
                half8 a2 = *(const half8*)((pAbase) + (size_t)(2 * (ASTR) + kt) * 512); \
                half8 a3 = *(const half8*)((pAbase) + (size_t)(3 * (ASTR) + kt) * 512); \
                half8 wo = *(const half8*)((pWbase) + (size_t)(2 * (WSTR) + kt) * 512); \
                __builtin_amdgcn_s_setprio(1);                                    \
                acco[0] = __builtin_amdgcn_mfma_f32_16x16x32_f16(wo, a0, acco[0], 0, 0, 0); \
                acco[1] = __builtin_amdgcn_mfma_f32_16x16x32_f16(wo, a1, acco[1], 0, 0, 0); \
                acco[2] = __builtin_amdgcn_mfma_f32_16x16x32_f16(wo, a2, acco[2], 0, 0, 0); \
                acco[3] = __builtin_amdgcn_mfma_f32_16x16x32_f16(wo, a3, acco[3], 0, 0, 0); \
                __builtin_amdgcn_s_setprio(0);                                    \
            }                                                                     \
            _Pragma("unroll")                                                     \
            for (int fm = 0; fm < 4; ++fm) {                                      \
                half4v oh;                                                        \
                _Pragma("unroll")                                                 \
                for (int j = 0; j < 4; ++j) {                                     \
                    float go = acco[fm][j] + bO[j];                               \
                    oh[j] = (_Float16)(fsig(go) * ftanh(c2[fm][j]));              \
                }                                                                 \
                *(half4v*)((DST) + ((fm * 8 + kt_o) * 64 + lane_o) * 8 + elem) = oh; \
            }                                                                     \
        }                                                                         \
    }

    // ---- layer 1: A from global xf (NT=4), W0f -> hP[0] ----
    {
        const _Float16* pA = xf + ((size_t)(b * 4) * 4) * 512 + lane * 8;
        const _Float16* pW = W0f + ((size_t)w * 4) * 512 + lane * 8;   // frag(g,kt): +(g*64+kt)*512
        LAYER_BODY(4, pA, 4, pW, 64, bs0, hP[0]);
    }
    __syncthreads();

    // ---- layer 2: A from hP[0] (LDS), W1f (NT=8) -> hP[1] ----
    {
        const _Float16* pW = W1f + ((size_t)w * 8) * 512 + lane * 8;   // frag(g,kt): +(g*128+kt)*512
        const _Float16* pL = hP[0] + lane * 8;
        LAYER_BODY(8, pL, 8, pW, 128, bs1, hP[1]);
    }
    __syncthreads();

    // ---- layer 3: A from hP[1] (LDS), W2f -> hP[0] ----
    {
        const _Float16* pW = W2f + ((size_t)w * 8) * 512 + lane * 8;
        const _Float16* pL = hP[1] + lane * 8;
        LAYER_BODY(8, pL, 8, pW, 128, bs2, hP[0]);
    }
    __syncthreads();

    // ---- fc + tanh-softmax-normalize: waves 0..3 (wave = 16-row group) ----
    if (w < 4) {
        const _Float16* pFW = fWf + lane * 8;          // frag(nf,kt): +(nf*8+kt)*512
        const _Float16* pL  = hP[0] + lane * 8;        // A frag (fmLocal=w, kt)
        const int ln = lrow;

        f32x4 acc[4];
#pragma unroll
        for (int nf = 0; nf < 4; ++nf) acc[nf] = (f32x4)0.f;
#pragma unroll
        for (int kt = 0; kt < 8; ++kt) {
            half8 ah = *(const half8*)(pL + (w * 8 + kt) * 512);
            __builtin_amdgcn_s_setprio(1);
#pragma unroll
            for (int nf = 0; nf < 4; ++nf) {
                half8 wf = *(const half8*)(pFW + (size_t)(nf * 8 + kt) * 512);
                acc[nf] = __builtin_amdgcn_mfma_f32_16x16x32_f16(ah, wf, acc[nf], 0, 0, 0);
            }
            __builtin_amdgcn_s_setprio(0);
        }

        float fb[4];
#pragma unroll
        for (int nf = 0; nf < 4; ++nf) fb[nf] = fcb[nf * 16 + ln];

        float tt[4][4], aa[4][4];
#pragma unroll
        for (int nf = 0; nf < 4; ++nf)
#pragma unroll
            for (int r = 0; r < 4; ++r) {
                float o = acc[nf][r] + fb[nf];
                tt[nf][r] = ftanh(o);
                aa[nf][r] = fabsf(o);
            }

        float mx[4];
#pragma unroll
        for (int r = 0; r < 4; ++r)
            mx[r] = fmaxf(fmaxf(aa[0][r], aa[1][r]), fmaxf(aa[2][r], aa[3][r]));
#pragma unroll
        for (int ofs = 1; ofs < 16; ofs <<= 1)
#pragma unroll
            for (int r = 0; r < 4; ++r) mx[r] = fmaxf(mx[r], __shfl_xor(mx[r], ofs, 64));

        float ee[4][4], Z[4];
#pragma unroll
        for (int r = 0; r < 4; ++r) Z[r] = 0.f;
#pragma unroll
        for (int nf = 0; nf < 4; ++nf)
#pragma unroll
            for (int r = 0; r < 4; ++r) { ee[nf][r] = __expf(aa[nf][r] - mx[r]); Z[r] += ee[nf][r]; }
#pragma unroll
        for (int ofs = 1; ofs < 16; ofs <<= 1)
#pragma unroll
            for (int r = 0; r < 4; ++r) Z[r] += __shfl_xor(Z[r], ofs, 64);

        float wv[4][4], S[4];
#pragma unroll
        for (int r = 0; r < 4; ++r) S[r] = 0.f;
#pragma unroll
        for (int r = 0; r < 4; ++r) {
            const float rz = frcp(Z[r]);
#pragma unroll
            for (int nf = 0; nf < 4; ++nf) { wv[nf][r] = tt[nf][r] * ee[nf][r] * rz; S[r] += fabsf(wv[nf][r]); }
        }
#pragma unroll
        for (int ofs = 1; ofs < 16; ofs <<= 1)
#pragma unroll
            for (int r = 0; r < 4; ++r) S[r] += __shfl_xor(S[r], ofs, 64);

#pragma unroll
        for (int r = 0; r < 4; ++r) {
            const float inv = frcp(fmaxf(S[r], 1e-12f));
            const int m = b * 64 + w * 16 + lkb * 4 + r;
#pragma unroll
            for (int nf = 0; nf < 4; ++nf)
                out[(size_t)m * 64 + nf * 16 + ln] = wv[nf][r] * inv;
        }
    }
#undef LAYER_BODY
}

// ---------------- launch ----------------

extern "C" void kernel_launch(void* const* d_in, const int* in_sizes, int n_in,
                              void* d_out, int out_size, void* d_ws, size_t ws_size,
                              hipStream_t stream) {
    const float* x    = (const float*)d_in[0];
    const float* Wih0 = (const float*)d_in[1];
    const float* bih0 = (const float*)d_in[3];
    const float* bhh0 = (const float*)d_in[4];
    const float* Wih1 = (const float*)d_in[5];
    const float* bih1 = (const float*)d_in[7];
    const float* bhh1 = (const float*)d_in[8];
    const float* Wih2 = (const float*)d_in[9];
    const float* bih2 = (const float*)d_in[11];
    const float* bhh2 = (const float*)d_in[12];
    const float* fcW  = (const float*)d_in[13];
    const float* fcb  = (const float*)d_in[14];

    char* ws = (char*)d_ws;
    _Float16* xf  = (_Float16*)(ws);                   // 4 MB frag-linear
    _Float16* W0f = (_Float16*)(ws + (4u << 20));      // 192 KB
    _Float16* W1f = (_Float16*)(ws + (5u << 20));      // 384 KB
    _Float16* W2f = (_Float16*)(ws + (6u << 20));      // 384 KB
    _Float16* fWf = (_Float16*)(ws + (7u << 20));      // 32 KB frag-linear
    float*    bs0 = (float*)(ws + (8u << 20));
    float*    bs1 = (float*)(ws + (8u << 20) + 4096);
    float*    bs2 = (float*)(ws + (8u << 20) + 8192);
    float*    outp = (float*)d_out;

    prep_all_kernel<<<dim3((PS5 + 255) / 256), dim3(256), 0, stream>>>(
        x, Wih0, bih0, bhh0, Wih1, bih1, bhh1, Wih2, bih2, bhh2, fcW,
        xf, W0f, W1f, W2f, bs0, bs1, bs2, fWf);

    mega_kernel<<<dim3(NROWS / 64), dim3(1024), 0, stream>>>(
        xf, W0f, bs0, W1f, bs1, W2f, bs2, fWf, fcb, outp);
}

// Round 24
// 39.428 us; speedup vs baseline: 1.0378x; 1.0378x over previous
//
#include <hip/hip_runtime.h>
#include <cstdint>
#include <cstddef>

// LSTMCreature, seq_len=1, h0=c0=0:
//   per layer: g = x @ Wih(gate rows).T + (bih+bhh); h = sig(go)*tanh(sig(gi)*tanh(gg))
//   f-gate skipped (multiplies c0=0), W_hh unused (h0=0).
// R24 = R22 RESTORED (best measured: 39.5us). Full fusion (3 layers + fc in
// one kernel, h ping-pong in LDS frag layout), frag-linear operands, rcp
// epilogue, T5 setprio. R23's gate-split was null (40.9): the design is at
// its latency-structure knee; this is the final configuration.

#define NROWS 16384
#define HSZ   256

typedef _Float16 half8  __attribute__((ext_vector_type(8)));
typedef _Float16 half4v __attribute__((ext_vector_type(4)));
typedef float    f32x4  __attribute__((ext_vector_type(4)));

__device__ __forceinline__ float frcp(float x)  { return __builtin_amdgcn_rcpf(x); }
__device__ __forceinline__ float fsig(float x)  { return frcp(1.f + __expf(-x)); }
__device__ __forceinline__ float ftanh(float x) { return 1.f - 2.f * frcp(__expf(2.f * x) + 1.f); }

__device__ __forceinline__ int gate_remap(int row) {   // 768-row id -> 1024-row src (gates i,g,o)
    int g8 = row >> 8;
    int gate = (g8 == 0) ? 0 : g8 + 1;
    return gate * 256 + (row & 255);
}

// ---------------- fused prep: everything -> frag-linear fp16 ----------------
// frag layout: elem (row,k) -> ((ru*NT+kt)*64 + lane)*8 + (k&7),
// lane = (row&15) | (((k>>3)&3)<<4), ru = row>>4, kt = k>>5.

#define PS0 262144            /* x: 16384*128/8 half8-groups */
#define PS1 (PS0 + 12288)     /* W0: 768*128/8 */
#define PS2 (PS1 + 24576)     /* W1: 768*256/8 */
#define PS3 (PS2 + 24576)     /* W2 */
#define PS4 (PS3 + 2304)      /* bsums */
#define PS5 (PS4 + 2048)      /* fcW: 64*256/8 frag-linear */

__global__ __launch_bounds__(256)
void prep_all_kernel(const float* __restrict__ x,
                     const float* __restrict__ W0, const float* __restrict__ b0i, const float* __restrict__ b0h,
                     const float* __restrict__ W1, const float* __restrict__ b1i, const float* __restrict__ b1h,
                     const float* __restrict__ W2, const float* __restrict__ b2i, const float* __restrict__ b2h,
                     const float* __restrict__ fcW,
                     _Float16* __restrict__ xf,
                     _Float16* __restrict__ W0f, _Float16* __restrict__ W1f, _Float16* __restrict__ W2f,
                     float* __restrict__ bs0, float* __restrict__ bs1, float* __restrict__ bs2,
                     _Float16* __restrict__ fWf)
{
    const int gid = blockIdx.x * 256 + threadIdx.x;
    if (gid < PS0) {
        int row = gid >> 4, kg = gid & 15;            // kg: 8-elem k-group
        const float* s = x + (size_t)row * 128 + kg * 8;
        f32x4 v0 = *(const f32x4*)s, v1 = *(const f32x4*)(s + 4);
        half8 h;
#pragma unroll
        for (int j = 0; j < 4; ++j) { h[j] = (_Float16)v0[j]; h[4 + j] = (_Float16)v1[j]; }
        int lane = (row & 15) | ((kg & 3) << 4);
        size_t idx = (((size_t)(row >> 4) * 4 + (kg >> 2)) * 64 + lane) * 8;
        *(half8*)(xf + idx) = h;
    } else if (gid < PS3) {
        const float* W; _Float16* Wf; int j, K, r768, kg, NTw;
        if (gid < PS1)      { j = gid - PS0; K = 128; W = W0; Wf = W0f; r768 = j >> 4; kg = j & 15; NTw = 4; }
        else if (gid < PS2) { j = gid - PS1; K = 256; W = W1; Wf = W1f; r768 = j >> 5; kg = j & 31; NTw = 8; }
        else                { j = gid - PS2; K = 256; W = W2; Wf = W2f; r768 = j >> 5; kg = j & 31; NTw = 8; }
        int src = gate_remap(r768);
        const float* s = W + (size_t)src * K + kg * 8;
        f32x4 v0 = *(const f32x4*)s, v1 = *(const f32x4*)(s + 4);
        half8 h;
#pragma unroll
        for (int jj = 0; jj < 4; ++jj) { h[jj] = (_Float16)v0[jj]; h[4 + jj] = (_Float16)v1[jj]; }
        int lane = (r768 & 15) | ((kg & 3) << 4);
        size_t idx = (((size_t)(r768 >> 4) * NTw + (kg >> 2)) * 64 + lane) * 8;
        *(half8*)(Wf + idx) = h;
    } else if (gid < PS4) {
        int j = gid - PS3;
        int l = (j >= 1536) ? 2 : (j >= 768 ? 1 : 0);
        int r = j - l * 768;
        int src = gate_remap(r);
        const float* bi = (l == 0) ? b0i : (l == 1) ? b1i : b2i;
        const float* bh = (l == 0) ? b0h : (l == 1) ? b1h : b2h;
        float* bs       = (l == 0) ? bs0 : (l == 1) ? bs1 : bs2;
        bs[r] = bi[src] + bh[src];
    } else if (gid < PS5) {
        int j = gid - PS4;            // 0..2047: fcW 64 rows x 32 kgroups -> frag-linear
        int r64 = j >> 5, kg = j & 31;
        const float* s = fcW + (size_t)r64 * 256 + kg * 8;
        f32x4 v0 = *(const f32x4*)s, v1 = *(const f32x4*)(s + 4);
        half8 h;
#pragma unroll
        for (int jj = 0; jj < 4; ++jj) { h[jj] = (_Float16)v0[jj]; h[4 + jj] = (_Float16)v1[jj]; }
        int lane = (r64 & 15) | ((kg & 3) << 4);
        size_t idx = (((size_t)(r64 >> 4) * 8 + (kg >> 2)) * 64 + lane) * 8;
        *(half8*)(fWf + idx) = h;
    }
}

// ---------------- mega kernel: 3 layers + fc, one block per 64-row slab ----------------
// 1024 threads = 16 waves; wave w = n-unit nu (0..15). Block b owns rows
// b*64..b*64+63. h1/h2/h3 ping-pong in LDS frag layout:
//   frag (fmLocal, kt) at ((fmLocal*8 + kt)*64 + lane)*8 halfs.

__global__ __launch_bounds__(1024, 4)
void mega_kernel(const _Float16* __restrict__ xf,
                 const _Float16* __restrict__ W0f, const float* __restrict__ bs0,
                 const _Float16* __restrict__ W1f, const float* __restrict__ bs1,
                 const _Float16* __restrict__ W2f, const float* __restrict__ bs2,
                 const _Float16* __restrict__ fWf, const float* __restrict__ fcb,
                 float* __restrict__ out)
{
    __shared__ __align__(16) _Float16 hP[2][64 * 256];   // 32KB each, frag layout

    const int t    = threadIdx.x;
    const int lane = t & 63;
    const int w    = t >> 6;        // wave = nu
    const int lrow = lane & 15;
    const int lkb  = lane >> 4;
    const int b    = blockIdx.x;

    const int kt_o   = w >> 1;
    const int lane_o = lrow | ((((w & 1) << 1) | (lkb >> 1)) << 4);
    const int elem   = (lkb & 1) * 4;
    const int nbase  = w * 16 + lkb * 4;

#define LAYER_EPILOGUE(BS, DST)                                               \
    {                                                                         \
        const f32x4 bI = *(const f32x4*)((BS) + nbase);                       \
        const f32x4 bG = *(const f32x4*)((BS) + 256 + nbase);                 \
        const f32x4 bO = *(const f32x4*)((BS) + 512 + nbase);                 \
        _Pragma("unroll")                                                     \
        for (int fm = 0; fm < 4; ++fm) {                                      \
            half4v oh;                                                        \
            _Pragma("unroll")                                                 \
            for (int j = 0; j < 4; ++j) {                                     \
                float gi = acc[0][fm][j] + bI[j];                             \
                float gg = acc[1][fm][j] + bG[j];                             \
                float go = acc[2][fm][j] + bO[j];                             \
                float c2 = fsig(gi) * ftanh(gg);                              \
                oh[j] = (_Float16)(fsig(go) * ftanh(c2));                     \
            }                                                                 \
            *(half4v*)((DST) + ((fm * 8 + kt_o) * 64 + lane_o) * 8 + elem) = oh; \
        }                                                                     \
    }

#define MFMA12(w0, w1, w2, a0, a1, a2, a3)                                        \
    __builtin_amdgcn_s_setprio(1);                                                \
    acc[0][0] = __builtin_amdgcn_mfma_f32_16x16x32_f16(w0, a0, acc[0][0], 0, 0, 0); \
    acc[0][1] = __builtin_amdgcn_mfma_f32_16x16x32_f16(w0, a1, acc[0][1], 0, 0, 0); \
    acc[0][2] = __builtin_amdgcn_mfma_f32_16x16x32_f16(w0, a2, acc[0][2], 0, 0, 0); \
    acc[0][3] = __builtin_amdgcn_mfma_f32_16x16x32_f16(w0, a3, acc[0][3], 0, 0, 0); \
    acc[1][0] = __builtin_amdgcn_mfma_f32_16x16x32_f16(w1, a0, acc[1][0], 0, 0, 0); \
    acc[1][1] = __builtin_amdgcn_mfma_f32_16x16x32_f16(w1, a1, acc[1][1], 0, 0, 0); \
    acc[1][2] = __builtin_amdgcn_mfma_f32_16x16x32_f16(w1, a2, acc[1][2], 0, 0, 0); \
    acc[1][3] = __builtin_amdgcn_mfma_f32_16x16x32_f16(w1, a3, acc[1][3], 0, 0, 0); \
    acc[2][0] = __builtin_amdgcn_mfma_f32_16x16x32_f16(w2, a0, acc[2][0], 0, 0, 0); \
    acc[2][1] = __builtin_amdgcn_mfma_f32_16x16x32_f16(w2, a1, acc[2][1], 0, 0, 0); \
    acc[2][2] = __builtin_amdgcn_mfma_f32_16x16x32_f16(w2, a2, acc[2][2], 0, 0, 0); \
    acc[2][3] = __builtin_amdgcn_mfma_f32_16x16x32_f16(w2, a3, acc[2][3], 0, 0, 0); \
    __builtin_amdgcn_s_setprio(0)

    // ---- layer 1: A from global xf (NT=4), W0f -> hP[0] ----
    {
        const _Float16* pA = xf + ((size_t)(b * 4) * 4) * 512 + lane * 8;
        const _Float16* pW = W0f + ((size_t)w * 4) * 512 + lane * 8;   // frag(g,kt): +(g*64+kt)*512
        f32x4 acc[3][4];
#pragma unroll
        for (int g = 0; g < 3; ++g)
#pragma unroll
            for (int fm = 0; fm < 4; ++fm) acc[g][fm] = (f32x4)0.f;
#pragma unroll
        for (int kt = 0; kt < 4; ++kt) {
            half8 a0 = *(const half8*)(pA + (size_t)(0 * 4 + kt) * 512);
            half8 a1 = *(const half8*)(pA + (size_t)(1 * 4 + kt) * 512);
            half8 a2 = *(const half8*)(pA + (size_t)(2 * 4 + kt) * 512);
            half8 a3 = *(const half8*)(pA + (size_t)(3 * 4 + kt) * 512);
            half8 w0 = *(const half8*)(pW + (size_t)(0 * 64 + kt) * 512);
            half8 w1 = *(const half8*)(pW + (size_t)(1 * 64 + kt) * 512);
            half8 w2 = *(const half8*)(pW + (size_t)(2 * 64 + kt) * 512);
            MFMA12(w0, w1, w2, a0, a1, a2, a3);
        }
        LAYER_EPILOGUE(bs0, hP[0]);
    }
    __syncthreads();

    // ---- layer 2: A from hP[0] (LDS), W1f (NT=8) -> hP[1] ----
    {
        const _Float16* pW = W1f + ((size_t)w * 8) * 512 + lane * 8;   // frag(g,kt): +(g*128+kt)*512
        const _Float16* pL = hP[0] + lane * 8;
        f32x4 acc[3][4];
#pragma unroll
        for (int g = 0; g < 3; ++g)
#pragma unroll
            for (int fm = 0; fm < 4; ++fm) acc[g][fm] = (f32x4)0.f;
#pragma unroll
        for (int kt = 0; kt < 8; ++kt) {
            half8 a0 = *(const half8*)(pL + (0 * 8 + kt) * 512);
            half8 a1 = *(const half8*)(pL + (1 * 8 + kt) * 512);
            half8 a2 = *(const half8*)(pL + (2 * 8 + kt) * 512);
            half8 a3 = *(const half8*)(pL + (3 * 8 + kt) * 512);
            half8 w0 = *(const half8*)(pW + (size_t)(0 * 128 + kt) * 512);
            half8 w1 = *(const half8*)(pW + (size_t)(1 * 128 + kt) * 512);
            half8 w2 = *(const half8*)(pW + (size_t)(2 * 128 + kt) * 512);
            MFMA12(w0, w1, w2, a0, a1, a2, a3);
        }
        LAYER_EPILOGUE(bs1, hP[1]);
    }
    __syncthreads();

    // ---- layer 3: A from hP[1] (LDS), W2f -> hP[0] ----
    {
        const _Float16* pW = W2f + ((size_t)w * 8) * 512 + lane * 8;
        const _Float16* pL = hP[1] + lane * 8;
        f32x4 acc[3][4];
#pragma unroll
        for (int g = 0; g < 3; ++g)
#pragma unroll
            for (int fm = 0; fm < 4; ++fm) acc[g][fm] = (f32x4)0.f;
#pragma unroll
        for (int kt = 0; kt < 8; ++kt) {
            half8 a0 = *(const half8*)(pL + (0 * 8 + kt) * 512);
            half8 a1 = *(const half8*)(pL + (1 * 8 + kt) * 512);
            half8 a2 = *(const half8*)(pL + (2 * 8 + kt) * 512);
            half8 a3 = *(const half8*)(pL + (3 * 8 + kt) * 512);
            half8 w0 = *(const half8*)(pW + (size_t)(0 * 128 + kt) * 512);
            half8 w1 = *(const half8*)(pW + (size_t)(1 * 128 + kt) * 512);
            half8 w2 = *(const half8*)(pW + (size_t)(2 * 128 + kt) * 512);
            MFMA12(w0, w1, w2, a0, a1, a2, a3);
        }
        LAYER_EPILOGUE(bs2, hP[0]);
    }
    __syncthreads();

    // ---- fc + tanh-softmax-normalize: waves 0..3 (wave = 16-row group) ----
    if (w < 4) {
        const _Float16* pFW = fWf + lane * 8;          // frag(nf,kt): +(nf*8+kt)*512
        const _Float16* pL  = hP[0] + lane * 8;        // A frag (fmLocal=w, kt)
        const int ln = lrow;

        f32x4 acc[4];
#pragma unroll
        for (int nf = 0; nf < 4; ++nf) acc[nf] = (f32x4)0.f;
#pragma unroll
        for (int kt = 0; kt < 8; ++kt) {
            half8 ah = *(const half8*)(pL + (w * 8 + kt) * 512);
            __builtin_amdgcn_s_setprio(1);
#pragma unroll
            for (int nf = 0; nf < 4; ++nf) {
                half8 wf = *(const half8*)(pFW + (size_t)(nf * 8 + kt) * 512);
                acc[nf] = __builtin_amdgcn_mfma_f32_16x16x32_f16(ah, wf, acc[nf], 0, 0, 0);
            }
            __builtin_amdgcn_s_setprio(0);
        }

        float fb[4];
#pragma unroll
        for (int nf = 0; nf < 4; ++nf) fb[nf] = fcb[nf * 16 + ln];

        float tt[4][4], aa[4][4];
#pragma unroll
        for (int nf = 0; nf < 4; ++nf)
#pragma unroll
            for (int r = 0; r < 4; ++r) {
                float o = acc[nf][r] + fb[nf];
                tt[nf][r] = ftanh(o);
                aa[nf][r] = fabsf(o);
            }

        float mx[4];
#pragma unroll
        for (int r = 0; r < 4; ++r)
            mx[r] = fmaxf(fmaxf(aa[0][r], aa[1][r]), fmaxf(aa[2][r], aa[3][r]));
#pragma unroll
        for (int ofs = 1; ofs < 16; ofs <<= 1)
#pragma unroll
            for (int r = 0; r < 4; ++r) mx[r] = fmaxf(mx[r], __shfl_xor(mx[r], ofs, 64));

        float ee[4][4], Z[4];
#pragma unroll
        for (int r = 0; r < 4; ++r) Z[r] = 0.f;
#pragma unroll
        for (int nf = 0; nf < 4; ++nf)
#pragma unroll
            for (int r = 0; r < 4; ++r) { ee[nf][r] = __expf(aa[nf][r] - mx[r]); Z[r] += ee[nf][r]; }
#pragma unroll
        for (int ofs = 1; ofs < 16; ofs <<= 1)
#pragma unroll
            for (int r = 0; r < 4; ++r) Z[r] += __shfl_xor(Z[r], ofs, 64);

        float wv[4][4], S[4];
#pragma unroll
        for (int r = 0; r < 4; ++r) S[r] = 0.f;
#pragma unroll
        for (int r = 0; r < 4; ++r) {
            const float rz = frcp(Z[r]);
#pragma unroll
            for (int nf = 0; nf < 4; ++nf) { wv[nf][r] = tt[nf][r] * ee[nf][r] * rz; S[r] += fabsf(wv[nf][r]); }
        }
#pragma unroll
        for (int ofs = 1; ofs < 16; ofs <<= 1)
#pragma unroll
            for (int r = 0; r < 4; ++r) S[r] += __shfl_xor(S[r], ofs, 64);

#pragma unroll
        for (int r = 0; r < 4; ++r) {
            const float inv = frcp(fmaxf(S[r], 1e-12f));
            const int m = b * 64 + w * 16 + lkb * 4 + r;
#pragma unroll
            for (int nf = 0; nf < 4; ++nf)
                out[(size_t)m * 64 + nf * 16 + ln] = wv[nf][r] * inv;
        }
    }
#undef LAYER_EPILOGUE
#undef MFMA12
}

// ---------------- launch ----------------

extern "C" void kernel_launch(void* const* d_in, const int* in_sizes, int n_in,
                              void* d_out, int out_size, void* d_ws, size_t ws_size,
                              hipStream_t stream) {
    const float* x    = (const float*)d_in[0];
    const float* Wih0 = (const float*)d_in[1];
    const float* bih0 = (const float*)d_in[3];
    const float* bhh0 = (const float*)d_in[4];
    const float* Wih1 = (const float*)d_in[5];
    const float* bih1 = (const float*)d_in[7];
    const float* bhh1 = (const float*)d_in[8];
    const float* Wih2 = (const float*)d_in[9];
    const float* bih2 = (const float*)d_in[11];
    const float* bhh2 = (const float*)d_in[12];
    const float* fcW  = (const float*)d_in[13];
    const float* fcb  = (const float*)d_in[14];

    char* ws = (char*)d_ws;
    _Float16* xf  = (_Float16*)(ws);                   // 4 MB frag-linear
    _Float16* W0f = (_Float16*)(ws + (4u << 20));      // 192 KB
    _Float16* W1f = (_Float16*)(ws + (5u << 20));      // 384 KB
    _Float16* W2f = (_Float16*)(ws + (6u << 20));      // 384 KB
    _Float16* fWf = (_Float16*)(ws + (7u << 20));      // 32 KB frag-linear
    float*    bs0 = (float*)(ws + (8u << 20));
    float*    bs1 = (float*)(ws + (8u << 20) + 4096);
    float*    bs2 = (float*)(ws + (8u << 20) + 8192);
    float*    outp = (float*)d_out;

    prep_all_kernel<<<dim3((PS5 + 255) / 256), dim3(256), 0, stream>>>(
        x, Wih0, bih0, bhh0, Wih1, bih1, bhh1, Wih2, bih2, bhh2, fcW,
        xf, W0f, W1f, W2f, bs0, bs1, bs2, fWf);

    mega_kernel<<<dim3(NROWS / 64), dim3(1024), 0, stream>>>(
        xf, W0f, bs0, W1f, bs1, W2f, bs2, fWf, fcb, outp);
}